// Round 13
// baseline (67.382 us; speedup 1.0000x reference)
//
#include <hip/hip_runtime.h>

// Problem constants (fixed by setup_inputs in the reference)
#define B_  8
#define N_  3072
#define C_  256
#define H_  128
#define W_  96
#define HW_ (H_ * W_)
#define NC_ (B_ * HW_)          // 98304 cells (~78% EMPTY: 0.25 tokens/cell)
#define NT_ (B_ * N_)           // 24576 tokens
#define EPSF 1e-6f

// Gaussian 3x3, sigma=2 (normalized): center, edge, corner
#define KW0 0.13080118f
#define KW1 0.11543166f
#define KW2 0.10186807f

// fused-kernel tiling: block = (b, y, 32-col x-tile, 128-ch group)
#define CG_ 128                 // channels per block (lane covers 2 via float2)
#define XT_ 32                  // x columns written per block
#define XS_ 34                  // staged columns (32 + 2 halo)
#define CPB 132                 // bf16 channel pad (row = 264 B; breaks pow2 banks)

// ws layout (u32 units) — identical to the round-4-proven 900,104 B layout.
#define OFF_ASTART 0
#define OFF_ACUR   (NC_ + 1)
#define OFF_BSUM   (2 * NC_ + 1)
#define OFF_BOFF   (2 * NC_ + 1 + 384)
#define OFF_TOKS   (2 * NC_ + 1 + 768)
// total = 2*NC_+1+768+NT_ = 221953 u32 = 887,812 B

__device__ __forceinline__ unsigned f2bf(float f) {   // RNE f32->bf16 (low 16)
    const unsigned u = __float_as_uint(f);
    return (u + 0x7FFFu + ((u >> 16) & 1u)) >> 16;
}

__device__ __forceinline__ void token_cell(const float* __restrict__ loc, int token,
                                           int& b, int& ix, int& iy) {
    b = token / N_;
    const float lx = fminf(fmaxf(loc[2 * token + 0], -1.0f), 1.0f);
    const float ly = fminf(fmaxf(loc[2 * token + 1], -1.0f), 1.0f);
    const float px = 0.5f * (lx + 1.0f) * (float)W_ - 0.5f;
    const float py = 0.5f * (ly + 1.0f) * (float)H_ - 0.5f;
    ix = (int)rintf(px); ix = min(max(ix, 0), W_ - 1);   // rintf = round-half-even = jnp.round
    iy = (int)rintf(py); iy = min(max(iy, 0), H_ - 1);
}

// Pass 1: histogram tokens into cells
__global__ void count_k(const float* __restrict__ loc, unsigned* __restrict__ cnts) {
    const int token = blockIdx.x * 256 + threadIdx.x;   // NT_ threads
    int b, ix, iy;
    token_cell(loc, token, b, ix, iy);
    atomicAdd(&cnts[b * HW_ + iy * W_ + ix], 1u);
}

// Pass 2a: per-block (256-cell) sums
__global__ void scanA(const unsigned* __restrict__ cnts, unsigned* __restrict__ Bsum) {
    const int i = blockIdx.x * 256 + threadIdx.x;
    int c = (int)cnts[i];
    #pragma unroll
    for (int off = 32; off > 0; off >>= 1) c += __shfl_down(c, off, 64);
    __shared__ int s[4];
    if ((threadIdx.x & 63) == 0) s[threadIdx.x >> 6] = c;
    __syncthreads();
    if (threadIdx.x == 0) Bsum[blockIdx.x] = (unsigned)(s[0] + s[1] + s[2] + s[3]);
}

// Pass 2b: exclusive scan of the 384 block sums (single block)
__global__ void scanB(const unsigned* __restrict__ Bsum, unsigned* __restrict__ Boff) {
    __shared__ unsigned s[512];
    const int t = threadIdx.x;
    const unsigned v = (t < 384) ? Bsum[t] : 0u;
    s[t] = v;
    __syncthreads();
    #pragma unroll
    for (int off = 1; off < 512; off <<= 1) {
        const unsigned a = (t >= off) ? s[t - off] : 0u;
        __syncthreads();
        s[t] += a;
        __syncthreads();
    }
    if (t < 384) Boff[t] = s[t] - v;   // exclusive
}

// Pass 2c: per-block exclusive scan + block offset -> Astart (and cursor copy)
__global__ void scanC(const unsigned* __restrict__ Boff,
                      unsigned* __restrict__ Astart, unsigned* __restrict__ Acur) {
    __shared__ unsigned s[256];
    const int t = threadIdx.x;
    const int i = blockIdx.x * 256 + t;
    const unsigned v = Acur[i];        // counts currently live in Acur
    s[t] = v;
    __syncthreads();
    #pragma unroll
    for (int off = 1; off < 256; off <<= 1) {
        const unsigned a = (t >= off) ? s[t - off] : 0u;
        __syncthreads();
        s[t] += a;
        __syncthreads();
    }
    const unsigned excl = s[t] - v + Boff[blockIdx.x];
    Astart[i] = excl;
    Acur[i]   = excl;                  // cursor starts at bin start
    if (i == 0) Astart[NC_] = NT_;     // total
}

// Pass 3: scatter token ids (packed with x) into bins
__global__ void fill_bins(const float* __restrict__ loc,
                          unsigned* __restrict__ Acur, unsigned* __restrict__ toks) {
    const int token = blockIdx.x * 256 + threadIdx.x;
    int b, ix, iy;
    token_cell(loc, token, b, ix, iy);
    const unsigned pos = atomicAdd(&Acur[b * HW_ + iy * W_ + ix], 1u);
    toks[pos] = ((unsigned)ix << 20) | (unsigned)token;
}

// Gather one row's 34-col window into an LDS slot (128 channels, bf16).
// One 35-lane coalesced Astart read gives the nonempty bitmask (ballot of the
// shfl diff) + walk range; then a batch-4 contiguous CSR walk (toks broadcast,
// xf float2 = 8B/lane, 512B/wave per token) flushing packed bf16x2 means.
__device__ __forceinline__ void gather_row(const float* __restrict__ xf,
        const unsigned* __restrict__ Astart, const unsigned* __restrict__ toks,
        unsigned short* __restrict__ Ms, unsigned long long* __restrict__ cm,
        int b, int yg, int xs, int cg, int lane) {
    const int cellbase = b * HW_ + yg * W_;
    unsigned a = 0u;
    if (lane < XS_ + 1) {
        int g = xs - 1 + lane;                 // [xs-1, xs+33]
        g = min(max(g, 0), W_);                // Astart[cellbase+W_] = row end
        a = Astart[cellbase + g];
    }
    const unsigned an = __shfl_down(a, 1, 64);
    const unsigned long long mask = __ballot(lane < XS_ && an > a);
    if (lane == 0) *cm = mask;                 // clamped edges diff to 0
    const unsigned p0 = __shfl(a, 0, 64);
    const unsigned p1 = __shfl(a, XS_, 64);

    unsigned* msw = (unsigned*)Ms;             // u32 view: 66 words per column
    int cur_xi = -1;
    float acc0 = 0.0f, acc1 = 0.0f;
    unsigned cnt = 0u;
    for (unsigned p = p0; p < p1; p += 4) {
        unsigned vv[4]; float2 ff[4];
        #pragma unroll
        for (int j = 0; j < 4; ++j)
            if (p + j < p1) vv[j] = toks[p + j];
        #pragma unroll
        for (int j = 0; j < 4; ++j)
            if (p + j < p1)
                ff[j] = *(const float2*)&xf[(size_t)(vv[j] & 0xFFFFFu) * C_
                                            + cg * CG_ + 2 * lane];
        #pragma unroll
        for (int j = 0; j < 4; ++j) {
            if (p + j >= p1) break;
            const int xi = (int)(vv[j] >> 20) - xs + 1;   // in [0, 34)
            if (xi != cur_xi) {
                if (cur_xi >= 0) {
                    const float rcp = 1.0f / ((float)cnt + EPSF);
                    msw[cur_xi * (CPB / 2) + lane] =
                        f2bf(acc0 * rcp) | (f2bf(acc1 * rcp) << 16);
                }
                acc0 = acc1 = 0.0f; cnt = 0u; cur_xi = xi;
            }
            acc0 += ff[j].x; acc1 += ff[j].y; ++cnt;
        }
    }
    if (cur_xi >= 0) {
        const float rcp = 1.0f / ((float)cnt + EPSF);
        msw[cur_xi * (CPB / 2) + lane] = f2bf(acc0 * rcp) | (f2bf(acc1 * rcp) << 16);
    }
}

// unpack 4 bf16 (8B, aligned) -> 4 f32
__device__ __forceinline__ void bf4_to_f32(const unsigned short* p, float* f) {
    const uint2 v = *(const uint2*)p;
    f[0] = __uint_as_float(v.x << 16);
    f[1] = __uint_as_float(v.x & 0xFFFF0000u);
    f[2] = __uint_as_float(v.y << 16);
    f[3] = __uint_as_float(v.y & 0xFFFF0000u);
}

// Pass 4 (FUSED): waves 0-2 gather rows y-1..y+1 in PARALLEL (full 128-ch
// group each, float2 reads); fill threads map to a FIXED x column (weights
// decoded once from the ballot bitmasks) x 16 channels; single coalesced
// NCHW write. LDS ~26.4 KB -> 6 blocks/CU.
__global__ __launch_bounds__(256) void fused_k(const float* __restrict__ xf,
        const unsigned* __restrict__ Astart, const unsigned* __restrict__ toks,
        float* __restrict__ out) {
    const int blk = blockIdx.x;          // ((b*128 + y)*3 + xt)*2 + cg
    const int cg = blk & 1;
    const int t2 = blk >> 1;
    const int xt = t2 % 3;
    const int t3 = t2 / 3;
    const int y  = t3 & 127;
    const int b  = t3 >> 7;
    const int xs = xt * XT_;
    const int lane = threadIdx.x & 63;
    const int wv = threadIdx.x >> 6;

    __shared__ __align__(16) unsigned short means[3 * XS_ * CPB];   // 26928 B
    __shared__ unsigned long long cmask[3];

    // zero-init means (bf16 +0.0 = 0x0000); empty cells stay exactly 0
    {
        uint4* p4 = (uint4*)means;
        for (int i = threadIdx.x; i < 3 * XS_ * CPB / 8; i += 256)
            p4[i] = make_uint4(0u, 0u, 0u, 0u);
    }
    __syncthreads();

    // gather: wave r in {0,1,2} walks row y-1+r (writes its cmask via ballot)
    if (wv < 3) {
        const int yg = y - 1 + wv;
        if ((unsigned)yg < (unsigned)H_)
            gather_row(xf, Astart, toks, means + wv * XS_ * CPB, &cmask[wv],
                       b, yg, xs, cg, lane);
        else if (lane == 0) cmask[wv] = 0ULL;
    }
    __syncthreads();

    // fill + write: thread = fixed x column (xl), 16 channels (sub*16..+15)
    const int xl  = threadIdx.x & 31;
    const int sub = threadIdx.x >> 5;
    const int xi  = xl + 1;              // LDS column of the center cell
    const int c0  = sub * 16;
    const unsigned long long cm0 = cmask[0], cm1 = cmask[1], cm2 = cmask[2];
    const unsigned short* M0 = means;
    const unsigned short* M1 = means + XS_ * CPB;
    const unsigned short* M2 = means + 2 * XS_ * CPB;
    float* op = out + ((size_t)(b * C_ + cg * CG_ + c0)) * HW_
                    + (size_t)y * W_ + xs + xl;

    if ((cm1 >> xi) & 1ULL) {            // nonempty: copy normalized mean
        #pragma unroll
        for (int q = 0; q < 4; ++q) {
            float m[4];
            bf4_to_f32(&M1[xi * CPB + c0 + q * 4], m);
            #pragma unroll
            for (int k = 0; k < 4; ++k)
                op[(size_t)(q * 4 + k) * HW_] = m[k];
        }
    } else {                             // empty: gaussian-gated neighbor blend
        const float w00 = ((cm0 >> (xi - 1)) & 1ULL) ? KW2 : 0.0f;
        const float w01 = ((cm0 >> xi)       & 1ULL) ? KW1 : 0.0f;
        const float w02 = ((cm0 >> (xi + 1)) & 1ULL) ? KW2 : 0.0f;
        const float w10 = ((cm1 >> (xi - 1)) & 1ULL) ? KW1 : 0.0f;
        const float w12 = ((cm1 >> (xi + 1)) & 1ULL) ? KW1 : 0.0f;
        const float w20 = ((cm2 >> (xi - 1)) & 1ULL) ? KW2 : 0.0f;
        const float w21 = ((cm2 >> xi)       & 1ULL) ? KW1 : 0.0f;
        const float w22 = ((cm2 >> (xi + 1)) & 1ULL) ? KW2 : 0.0f;
        const float ms = ((w00 + w02) + (w20 + w22)) + ((w01 + w21) + (w10 + w12));
        const float inv = 1.0f / (ms + EPSF);   // ms==0 -> fs==0 -> 0
        #pragma unroll
        for (int q = 0; q < 4; ++q) {
            const int cq = c0 + q * 4;
            const int im = (xi - 1) * CPB + cq;
            const int ic = (xi    ) * CPB + cq;
            const int ip = (xi + 1) * CPB + cq;
            float a0[4], a1[4], a2[4], b0[4], b2[4], d0[4], d1[4], d2[4];
            bf4_to_f32(&M0[im], a0); bf4_to_f32(&M0[ic], a1); bf4_to_f32(&M0[ip], a2);
            bf4_to_f32(&M1[im], b0);                          bf4_to_f32(&M1[ip], b2);
            bf4_to_f32(&M2[im], d0); bf4_to_f32(&M2[ic], d1); bf4_to_f32(&M2[ip], d2);
            #pragma unroll
            for (int k = 0; k < 4; ++k) {
                const float fs = w00*a0[k] + w01*a1[k] + w02*a2[k]
                               + w10*b0[k] + w12*b2[k]
                               + w20*d0[k] + w21*d1[k] + w22*d2[k];
                op[(size_t)(q * 4 + k) * HW_] = fs * inv;
            }
        }
    }
}

extern "C" void kernel_launch(void* const* d_in, const int* in_sizes, int n_in,
                              void* d_out, int out_size, void* d_ws, size_t ws_size,
                              hipStream_t stream) {
    const float* x   = (const float*)d_in[0];   // (B, N, C) f32
    const float* loc = (const float*)d_in[1];   // (B, N, 2) f32
    float* out = (float*)d_out;                 // (B, C, H, W) f32

    unsigned* W32 = (unsigned*)d_ws;
    unsigned* Astart = W32 + OFF_ASTART;
    unsigned* Acur   = W32 + OFF_ACUR;
    unsigned* Bsum   = W32 + OFF_BSUM;
    unsigned* Boff   = W32 + OFF_BOFF;
    unsigned* toks   = W32 + OFF_TOKS;

    hipMemsetAsync(Acur, 0, (size_t)NC_ * sizeof(unsigned), stream);

    count_k  <<<NT_ / 256, 256, 0, stream>>>(loc, Acur);
    scanA    <<<NC_ / 256, 256, 0, stream>>>(Acur, Bsum);
    scanB    <<<1, 512, 0, stream>>>(Bsum, Boff);
    scanC    <<<NC_ / 256, 256, 0, stream>>>(Boff, Astart, Acur);
    fill_bins<<<NT_ / 256, 256, 0, stream>>>(loc, Acur, toks);

    // grid = 8*128*3*2 = 6144 blocks
    fused_k<<<B_ * H_ * 3 * 2, 256, 0, stream>>>(x, Astart, toks, out);
}

// Round 14
// 61.008 us; speedup vs baseline: 1.1045x; 1.1045x over previous
//
#include <hip/hip_runtime.h>

// Problem constants (fixed by setup_inputs in the reference)
#define B_  8
#define N_  3072
#define C_  256
#define H_  128
#define W_  96
#define HW_ (H_ * W_)
#define NC_ (B_ * HW_)          // 98304 cells (~78% EMPTY: 0.25 tokens/cell)
#define NT_ (B_ * N_)           // 24576 tokens
#define EPSF 1e-6f

// Gaussian 3x3, sigma=2 (normalized): center, edge, corner
#define KW0 0.13080118f
#define KW1 0.11543166f
#define KW2 0.10186807f

// fused-kernel tiling: block = (b, 2-row pair, 32-col x-tile, 128-ch group)
#define CG_ 128                 // channels per block (lane covers 2 via float2)
#define XT_ 32                  // x columns written per block
#define XS_ 34                  // staged columns (32 + 2 halo)
#define CPB 132                 // bf16 channel pad (row = 264 B; breaks pow2 banks)
#define RY_ 2                   // output rows per block (4 staged rows, 1 per wave)

// ws layout (u32 units) — round-4-proven layout (ws is actually ~384 MB).
#define OFF_ASTART 0
#define OFF_ACUR   (NC_ + 1)
#define OFF_BSUM   (2 * NC_ + 1)
#define OFF_BOFF   (2 * NC_ + 1 + 384)
#define OFF_TOKS   (2 * NC_ + 1 + 768)

__device__ __forceinline__ unsigned f2bf(float f) {   // RNE f32->bf16 (low 16)
    const unsigned u = __float_as_uint(f);
    return (u + 0x7FFFu + ((u >> 16) & 1u)) >> 16;
}

__device__ __forceinline__ void token_cell(const float* __restrict__ loc, int token,
                                           int& b, int& ix, int& iy) {
    b = token / N_;
    const float lx = fminf(fmaxf(loc[2 * token + 0], -1.0f), 1.0f);
    const float ly = fminf(fmaxf(loc[2 * token + 1], -1.0f), 1.0f);
    const float px = 0.5f * (lx + 1.0f) * (float)W_ - 0.5f;
    const float py = 0.5f * (ly + 1.0f) * (float)H_ - 0.5f;
    ix = (int)rintf(px); ix = min(max(ix, 0), W_ - 1);   // rintf = round-half-even = jnp.round
    iy = (int)rintf(py); iy = min(max(iy, 0), H_ - 1);
}

// Pass 1: histogram tokens into cells
__global__ void count_k(const float* __restrict__ loc, unsigned* __restrict__ cnts) {
    const int token = blockIdx.x * 256 + threadIdx.x;   // NT_ threads
    int b, ix, iy;
    token_cell(loc, token, b, ix, iy);
    atomicAdd(&cnts[b * HW_ + iy * W_ + ix], 1u);
}

// Pass 2a: per-block (256-cell) sums
__global__ void scanA(const unsigned* __restrict__ cnts, unsigned* __restrict__ Bsum) {
    const int i = blockIdx.x * 256 + threadIdx.x;
    int c = (int)cnts[i];
    #pragma unroll
    for (int off = 32; off > 0; off >>= 1) c += __shfl_down(c, off, 64);
    __shared__ int s[4];
    if ((threadIdx.x & 63) == 0) s[threadIdx.x >> 6] = c;
    __syncthreads();
    if (threadIdx.x == 0) Bsum[blockIdx.x] = (unsigned)(s[0] + s[1] + s[2] + s[3]);
}

// Pass 2b: exclusive scan of the 384 block sums (single block)
__global__ void scanB(const unsigned* __restrict__ Bsum, unsigned* __restrict__ Boff) {
    __shared__ unsigned s[512];
    const int t = threadIdx.x;
    const unsigned v = (t < 384) ? Bsum[t] : 0u;
    s[t] = v;
    __syncthreads();
    #pragma unroll
    for (int off = 1; off < 512; off <<= 1) {
        const unsigned a = (t >= off) ? s[t - off] : 0u;
        __syncthreads();
        s[t] += a;
        __syncthreads();
    }
    if (t < 384) Boff[t] = s[t] - v;   // exclusive
}

// Pass 2c: per-block exclusive scan + block offset -> Astart (and cursor copy)
__global__ void scanC(const unsigned* __restrict__ Boff,
                      unsigned* __restrict__ Astart, unsigned* __restrict__ Acur) {
    __shared__ unsigned s[256];
    const int t = threadIdx.x;
    const int i = blockIdx.x * 256 + t;
    const unsigned v = Acur[i];        // counts currently live in Acur
    s[t] = v;
    __syncthreads();
    #pragma unroll
    for (int off = 1; off < 256; off <<= 1) {
        const unsigned a = (t >= off) ? s[t - off] : 0u;
        __syncthreads();
        s[t] += a;
        __syncthreads();
    }
    const unsigned excl = s[t] - v + Boff[blockIdx.x];
    Astart[i] = excl;
    Acur[i]   = excl;                  // cursor starts at bin start
    if (i == 0) Astart[NC_] = NT_;     // total
}

// Pass 3: scatter token ids (packed with x) into bins
__global__ void fill_bins(const float* __restrict__ loc,
                          unsigned* __restrict__ Acur, unsigned* __restrict__ toks) {
    const int token = blockIdx.x * 256 + threadIdx.x;
    int b, ix, iy;
    token_cell(loc, token, b, ix, iy);
    const unsigned pos = atomicAdd(&Acur[b * HW_ + iy * W_ + ix], 1u);
    toks[pos] = ((unsigned)ix << 20) | (unsigned)token;
}

// Gather one row's 34-col window into an LDS slot (128 channels, bf16).
// One 35-lane coalesced Astart read gives the nonempty bitmask (ballot of the
// shfl diff) + walk range; then a batch-4 contiguous CSR walk (toks broadcast,
// xf float2 = 8B/lane, 512B/wave per token) flushing packed bf16x2 means.
__device__ __forceinline__ void gather_row(const float* __restrict__ xf,
        const unsigned* __restrict__ Astart, const unsigned* __restrict__ toks,
        unsigned short* __restrict__ Ms, unsigned long long* __restrict__ cm,
        int b, int yg, int xs, int cg, int lane) {
    const int cellbase = b * HW_ + yg * W_;
    unsigned a = 0u;
    if (lane < XS_ + 1) {
        int g = xs - 1 + lane;                 // [xs-1, xs+33]
        g = min(max(g, 0), W_);                // Astart[cellbase+W_] = row end
        a = Astart[cellbase + g];
    }
    const unsigned an = __shfl_down(a, 1, 64);
    const unsigned long long mask = __ballot(lane < XS_ && an > a);
    if (lane == 0) *cm = mask;                 // clamped edges diff to 0
    const unsigned p0 = __shfl(a, 0, 64);
    const unsigned p1 = __shfl(a, XS_, 64);

    unsigned* msw = (unsigned*)Ms;             // u32 view: 66 words per column
    int cur_xi = -1;
    float acc0 = 0.0f, acc1 = 0.0f;
    unsigned cnt = 0u;
    for (unsigned p = p0; p < p1; p += 4) {
        unsigned vv[4]; float2 ff[4];
        #pragma unroll
        for (int j = 0; j < 4; ++j)
            if (p + j < p1) vv[j] = toks[p + j];
        #pragma unroll
        for (int j = 0; j < 4; ++j)
            if (p + j < p1)
                ff[j] = *(const float2*)&xf[(size_t)(vv[j] & 0xFFFFFu) * C_
                                            + cg * CG_ + 2 * lane];
        #pragma unroll
        for (int j = 0; j < 4; ++j) {
            if (p + j >= p1) break;
            const int xi = (int)(vv[j] >> 20) - xs + 1;   // in [0, 34)
            if (xi != cur_xi) {
                if (cur_xi >= 0) {
                    const float rcp = 1.0f / ((float)cnt + EPSF);
                    msw[cur_xi * (CPB / 2) + lane] =
                        f2bf(acc0 * rcp) | (f2bf(acc1 * rcp) << 16);
                }
                acc0 = acc1 = 0.0f; cnt = 0u; cur_xi = xi;
            }
            acc0 += ff[j].x; acc1 += ff[j].y; ++cnt;
        }
    }
    if (cur_xi >= 0) {
        const float rcp = 1.0f / ((float)cnt + EPSF);
        msw[cur_xi * (CPB / 2) + lane] = f2bf(acc0 * rcp) | (f2bf(acc1 * rcp) << 16);
    }
}

// unpack 4 bf16 (8B, aligned) -> 4 f32
__device__ __forceinline__ void bf4_to_f32(const unsigned short* p, float* f) {
    const uint2 v = *(const uint2*)p;
    f[0] = __uint_as_float(v.x << 16);
    f[1] = __uint_as_float(v.x & 0xFFFF0000u);
    f[2] = __uint_as_float(v.y << 16);
    f[3] = __uint_as_float(v.y & 0xFFFF0000u);
}

// Pass 4 (FUSED, 2 rows/block): all 4 waves gather rows y0-1..y0+2 in PARALLEL
// into 4 fixed LDS slots; fill threads map to a FIXED x column x 16 channels
// x 2 output rows (weights decoded once per row); single coalesced NCHW write.
// LDS ~35.9 KB -> 4 blocks/CU. Per output row: 2 walks (vs 3), 18 KB zeroed
// (vs 27), half the blocks.
__global__ __launch_bounds__(256) void fused_k(const float* __restrict__ xf,
        const unsigned* __restrict__ Astart, const unsigned* __restrict__ toks,
        float* __restrict__ out) {
    const int blk = blockIdx.x;          // ((b*64 + yp)*3 + xt)*2 + cg
    const int cg = blk & 1;
    const int t2 = blk >> 1;
    const int xt = t2 % 3;
    const int t3 = t2 / 3;
    const int yp = t3 & 63;
    const int b  = t3 >> 6;
    const int y0 = yp * RY_;
    const int xs = xt * XT_;
    const int lane = threadIdx.x & 63;
    const int wv = threadIdx.x >> 6;

    __shared__ __align__(16) unsigned short means[4 * XS_ * CPB];   // 35904 B
    __shared__ unsigned long long cmask[4];

    // zero-init means (bf16 +0.0 = 0x0000); empty cells stay exactly 0
    {
        uint4* p4 = (uint4*)means;
        for (int i = threadIdx.x; i < 4 * XS_ * CPB / 8; i += 256)
            p4[i] = make_uint4(0u, 0u, 0u, 0u);
    }
    __syncthreads();

    // gather: wave wv in {0..3} walks row y0-1+wv into slot wv (ballot cmask)
    {
        const int yg = y0 - 1 + wv;
        if ((unsigned)yg < (unsigned)H_)
            gather_row(xf, Astart, toks, means + wv * XS_ * CPB, &cmask[wv],
                       b, yg, xs, cg, lane);
        else if (lane == 0) cmask[wv] = 0ULL;
    }
    __syncthreads();

    // fill + write: thread = fixed x column (xl) x 16 channels x 2 rows
    const int xl  = threadIdx.x & 31;
    const int sub = threadIdx.x >> 5;
    const int xi  = xl + 1;              // LDS column of the center cell
    const int c0  = sub * 16;

    #pragma unroll
    for (int r = 0; r < RY_; ++r) {
        const int y = y0 + r;
        const unsigned long long cm0 = cmask[r], cm1 = cmask[r + 1],
                                 cm2 = cmask[r + 2];
        const unsigned short* M0 = means + (r    ) * XS_ * CPB;
        const unsigned short* M1 = means + (r + 1) * XS_ * CPB;
        const unsigned short* M2 = means + (r + 2) * XS_ * CPB;
        float* op = out + ((size_t)(b * C_ + cg * CG_ + c0)) * HW_
                        + (size_t)y * W_ + xs + xl;

        if ((cm1 >> xi) & 1ULL) {        // nonempty: copy normalized mean
            #pragma unroll
            for (int q = 0; q < 4; ++q) {
                float m[4];
                bf4_to_f32(&M1[xi * CPB + c0 + q * 4], m);
                #pragma unroll
                for (int k = 0; k < 4; ++k)
                    op[(size_t)(q * 4 + k) * HW_] = m[k];
            }
        } else {                         // empty: gaussian-gated neighbor blend
            const float w00 = ((cm0 >> (xi - 1)) & 1ULL) ? KW2 : 0.0f;
            const float w01 = ((cm0 >> xi)       & 1ULL) ? KW1 : 0.0f;
            const float w02 = ((cm0 >> (xi + 1)) & 1ULL) ? KW2 : 0.0f;
            const float w10 = ((cm1 >> (xi - 1)) & 1ULL) ? KW1 : 0.0f;
            const float w12 = ((cm1 >> (xi + 1)) & 1ULL) ? KW1 : 0.0f;
            const float w20 = ((cm2 >> (xi - 1)) & 1ULL) ? KW2 : 0.0f;
            const float w21 = ((cm2 >> xi)       & 1ULL) ? KW1 : 0.0f;
            const float w22 = ((cm2 >> (xi + 1)) & 1ULL) ? KW2 : 0.0f;
            const float ms = ((w00 + w02) + (w20 + w22))
                           + ((w01 + w21) + (w10 + w12));
            const float inv = 1.0f / (ms + EPSF);   // ms==0 -> fs==0 -> 0
            #pragma unroll
            for (int q = 0; q < 4; ++q) {
                const int cq = c0 + q * 4;
                const int im = (xi - 1) * CPB + cq;
                const int ic = (xi    ) * CPB + cq;
                const int ip = (xi + 1) * CPB + cq;
                float a0[4], a1[4], a2[4], b0[4], b2[4], d0[4], d1[4], d2[4];
                bf4_to_f32(&M0[im], a0); bf4_to_f32(&M0[ic], a1); bf4_to_f32(&M0[ip], a2);
                bf4_to_f32(&M1[im], b0);                          bf4_to_f32(&M1[ip], b2);
                bf4_to_f32(&M2[im], d0); bf4_to_f32(&M2[ic], d1); bf4_to_f32(&M2[ip], d2);
                #pragma unroll
                for (int k = 0; k < 4; ++k) {
                    const float fs = w00*a0[k] + w01*a1[k] + w02*a2[k]
                                   + w10*b0[k] + w12*b2[k]
                                   + w20*d0[k] + w21*d1[k] + w22*d2[k];
                    op[(size_t)(q * 4 + k) * HW_] = fs * inv;
                }
            }
        }
    }
}

extern "C" void kernel_launch(void* const* d_in, const int* in_sizes, int n_in,
                              void* d_out, int out_size, void* d_ws, size_t ws_size,
                              hipStream_t stream) {
    const float* x   = (const float*)d_in[0];   // (B, N, C) f32
    const float* loc = (const float*)d_in[1];   // (B, N, 2) f32
    float* out = (float*)d_out;                 // (B, C, H, W) f32

    unsigned* W32 = (unsigned*)d_ws;
    unsigned* Astart = W32 + OFF_ASTART;
    unsigned* Acur   = W32 + OFF_ACUR;
    unsigned* Bsum   = W32 + OFF_BSUM;
    unsigned* Boff   = W32 + OFF_BOFF;
    unsigned* toks   = W32 + OFF_TOKS;

    hipMemsetAsync(Acur, 0, (size_t)NC_ * sizeof(unsigned), stream);

    count_k  <<<NT_ / 256, 256, 0, stream>>>(loc, Acur);
    scanA    <<<NC_ / 256, 256, 0, stream>>>(Acur, Bsum);
    scanB    <<<1, 512, 0, stream>>>(Bsum, Boff);
    scanC    <<<NC_ / 256, 256, 0, stream>>>(Boff, Astart, Acur);
    fill_bins<<<NT_ / 256, 256, 0, stream>>>(loc, Acur, toks);

    // grid = 8*64*3*2 = 3072 blocks
    fused_k<<<B_ * (H_ / RY_) * 3 * 2, 256, 0, stream>>>(x, Astart, toks, out);
}

// Round 15
// 59.926 us; speedup vs baseline: 1.1244x; 1.0181x over previous
//
#include <hip/hip_runtime.h>

// Problem constants (fixed by setup_inputs in the reference)
#define B_  8
#define N_  3072
#define C_  256
#define H_  128
#define W_  96
#define HW_ (H_ * W_)
#define NC_ (B_ * HW_)          // 98304 cells (~78% EMPTY: 0.25 tokens/cell)
#define NT_ (B_ * N_)           // 24576 tokens
#define EPSF 1e-6f

// Gaussian 3x3, sigma=2 (normalized): center, edge, corner
#define KW0 0.13080118f
#define KW1 0.11543166f
#define KW2 0.10186807f

// fused-kernel tiling: block = (b, 2-row pair, 32-col x-tile, 128-ch group)
#define CG_ 128                 // channels per block (lane covers 2 via float2)
#define XT_ 32                  // x columns written per block
#define XS_ 34                  // staged columns (32 + 2 halo)
#define CPB 132                 // bf16 channel pad (row = 264 B; breaks pow2 banks)
#define RY_ 2                   // output rows per block (4 staged rows, 1 per wave)

// ws layout (u32 units) — round-4-proven layout (ws is actually ~384 MB).
#define OFF_ASTART 0
#define OFF_ACUR   (NC_ + 1)
#define OFF_BSUM   (2 * NC_ + 1)
#define OFF_BOFF   (2 * NC_ + 1 + 384)
#define OFF_TOKS   (2 * NC_ + 1 + 768)

__device__ __forceinline__ unsigned f2bf(float f) {   // RNE f32->bf16 (low 16)
    const unsigned u = __float_as_uint(f);
    return (u + 0x7FFFu + ((u >> 16) & 1u)) >> 16;
}

__device__ __forceinline__ void token_cell(const float* __restrict__ loc, int token,
                                           int& b, int& ix, int& iy) {
    b = token / N_;
    const float lx = fminf(fmaxf(loc[2 * token + 0], -1.0f), 1.0f);
    const float ly = fminf(fmaxf(loc[2 * token + 1], -1.0f), 1.0f);
    const float px = 0.5f * (lx + 1.0f) * (float)W_ - 0.5f;
    const float py = 0.5f * (ly + 1.0f) * (float)H_ - 0.5f;
    ix = (int)rintf(px); ix = min(max(ix, 0), W_ - 1);   // rintf = round-half-even = jnp.round
    iy = (int)rintf(py); iy = min(max(iy, 0), H_ - 1);
}

// Pass 1: histogram tokens into cells
__global__ void count_k(const float* __restrict__ loc, unsigned* __restrict__ cnts) {
    const int token = blockIdx.x * 256 + threadIdx.x;   // NT_ threads
    int b, ix, iy;
    token_cell(loc, token, b, ix, iy);
    atomicAdd(&cnts[b * HW_ + iy * W_ + ix], 1u);
}

// Pass 2a: per-block (256-cell) sums
__global__ void scanA(const unsigned* __restrict__ cnts, unsigned* __restrict__ Bsum) {
    const int i = blockIdx.x * 256 + threadIdx.x;
    int c = (int)cnts[i];
    #pragma unroll
    for (int off = 32; off > 0; off >>= 1) c += __shfl_down(c, off, 64);
    __shared__ int s[4];
    if ((threadIdx.x & 63) == 0) s[threadIdx.x >> 6] = c;
    __syncthreads();
    if (threadIdx.x == 0) Bsum[blockIdx.x] = (unsigned)(s[0] + s[1] + s[2] + s[3]);
}

// Pass 2b: exclusive scan of the 384 block sums (single block)
__global__ void scanB(const unsigned* __restrict__ Bsum, unsigned* __restrict__ Boff) {
    __shared__ unsigned s[512];
    const int t = threadIdx.x;
    const unsigned v = (t < 384) ? Bsum[t] : 0u;
    s[t] = v;
    __syncthreads();
    #pragma unroll
    for (int off = 1; off < 512; off <<= 1) {
        const unsigned a = (t >= off) ? s[t - off] : 0u;
        __syncthreads();
        s[t] += a;
        __syncthreads();
    }
    if (t < 384) Boff[t] = s[t] - v;   // exclusive
}

// Pass 2c: per-block exclusive scan + block offset -> Astart (and cursor copy)
__global__ void scanC(const unsigned* __restrict__ Boff,
                      unsigned* __restrict__ Astart, unsigned* __restrict__ Acur) {
    __shared__ unsigned s[256];
    const int t = threadIdx.x;
    const int i = blockIdx.x * 256 + t;
    const unsigned v = Acur[i];        // counts currently live in Acur
    s[t] = v;
    __syncthreads();
    #pragma unroll
    for (int off = 1; off < 256; off <<= 1) {
        const unsigned a = (t >= off) ? s[t - off] : 0u;
        __syncthreads();
        s[t] += a;
        __syncthreads();
    }
    const unsigned excl = s[t] - v + Boff[blockIdx.x];
    Astart[i] = excl;
    Acur[i]   = excl;                  // cursor starts at bin start
    if (i == 0) Astart[NC_] = NT_;     // total
}

// Pass 3: scatter token ids (packed with x) into bins
__global__ void fill_bins(const float* __restrict__ loc,
                          unsigned* __restrict__ Acur, unsigned* __restrict__ toks) {
    const int token = blockIdx.x * 256 + threadIdx.x;
    int b, ix, iy;
    token_cell(loc, token, b, ix, iy);
    const unsigned pos = atomicAdd(&Acur[b * HW_ + iy * W_ + ix], 1u);
    toks[pos] = ((unsigned)ix << 20) | (unsigned)token;
}

// unpack 4 bf16 (8B, aligned) -> 4 f32
__device__ __forceinline__ void bf4_to_f32(const unsigned short* p, float* f) {
    const uint2 v = *(const uint2*)p;
    f[0] = __uint_as_float(v.x << 16);
    f[1] = __uint_as_float(v.x & 0xFFFF0000u);
    f[2] = __uint_as_float(v.y << 16);
    f[3] = __uint_as_float(v.y & 0xFFFF0000u);
}

// Pass 4 (FUSED, 2 rows/block, branchless fill):
//   (1) per-wave Astart stage + cmask ballot (latency hidden under LDS init)
//   (2) zero-init bf16 means; barrier A
//   (3) wave 0 builds the per-cell 9-coef table (channel-invariant, once);
//       all waves walk their row's contiguous CSR range flushing bf16 means
//   (4) barrier B; fill = uniform 9-term dot product per ch-quad, no branches.
__global__ __launch_bounds__(256) void fused_k(const float* __restrict__ xf,
        const unsigned* __restrict__ Astart, const unsigned* __restrict__ toks,
        float* __restrict__ out) {
    const int blk = blockIdx.x;          // ((b*64 + yp)*3 + xt)*2 + cg
    const int cg = blk & 1;
    const int t2 = blk >> 1;
    const int xt = t2 % 3;
    const int t3 = t2 / 3;
    const int yp = t3 & 63;
    const int b  = t3 >> 6;
    const int y0 = yp * RY_;
    const int xs = xt * XT_;
    const int lane = threadIdx.x & 63;
    const int wv = threadIdx.x >> 6;

    __shared__ __align__(16) unsigned short means[4 * XS_ * CPB];   // 35904 B
    __shared__ unsigned long long cmask[4];
    __shared__ float coef[RY_][XT_][10];                            // 2560 B

    // (1) per-wave Astart stage for row y0-1+wv (issues early; latency
    //     overlaps the zero-init below). OOB rows -> cmask 0, empty range.
    const int yg = y0 - 1 + wv;
    const bool inrow = ((unsigned)yg < (unsigned)H_);
    unsigned p0, p1;
    {
        unsigned a = 0u;
        if (inrow && lane < XS_ + 1) {
            int g = xs - 1 + lane;                 // [xs-1, xs+33]
            g = min(max(g, 0), W_);                // Astart[..+W_] = row end
            a = Astart[b * HW_ + yg * W_ + g];
        }
        const unsigned an = __shfl_down(a, 1, 64);
        const unsigned long long mask = __ballot(lane < XS_ && an > a);
        if (lane == 0) cmask[wv] = mask;
        p0 = __shfl(a, 0, 64);
        p1 = __shfl(a, XS_, 64);
    }

    // (2) zero-init means (bf16 +0.0 = 0x0000); empty cells stay exactly 0
    {
        uint4* p4 = (uint4*)means;
        for (int i = threadIdx.x; i < 4 * XS_ * CPB / 8; i += 256)
            p4[i] = make_uint4(0u, 0u, 0u, 0u);
    }
    __syncthreads();   // A: init + cmask ready

    // (3a) wave 0: per-cell coefficient table (64 cells = 2 rows x 32 x)
    if (wv == 0) {
        const int r  = lane >> 5;
        const int xl = lane & 31;
        const int xi = xl + 1;
        const unsigned long long cm0 = cmask[r], cm1 = cmask[r + 1],
                                 cm2 = cmask[r + 2];
        const float w0 = ((cm0 >> (xi - 1)) & 1ULL) ? KW2 : 0.0f;
        const float w1 = ((cm0 >> xi)       & 1ULL) ? KW1 : 0.0f;
        const float w2 = ((cm0 >> (xi + 1)) & 1ULL) ? KW2 : 0.0f;
        const float w3 = ((cm1 >> (xi - 1)) & 1ULL) ? KW1 : 0.0f;
        const float w5 = ((cm1 >> (xi + 1)) & 1ULL) ? KW1 : 0.0f;
        const float w6 = ((cm2 >> (xi - 1)) & 1ULL) ? KW2 : 0.0f;
        const float w7 = ((cm2 >> xi)       & 1ULL) ? KW1 : 0.0f;
        const float w8 = ((cm2 >> (xi + 1)) & 1ULL) ? KW2 : 0.0f;
        const bool ne  = (cm1 >> xi) & 1ULL;
        const float ms = ((w0 + w2) + (w6 + w8)) + ((w1 + w7) + (w3 + w5));
        const float inv = ne ? 0.0f : 1.0f / (ms + EPSF);   // ms==0 -> all 0
        coef[r][xl][0] = w0 * inv;
        coef[r][xl][1] = w1 * inv;
        coef[r][xl][2] = w2 * inv;
        coef[r][xl][3] = w3 * inv;
        coef[r][xl][4] = ne ? 1.0f : 0.0f;   // self (nonempty copy)
        coef[r][xl][5] = w5 * inv;
        coef[r][xl][6] = w6 * inv;
        coef[r][xl][7] = w7 * inv;
        coef[r][xl][8] = w8 * inv;
    }

    // (3b) all waves: batch-4 contiguous CSR walk of [p0,p1) into slot wv
    if (inrow) {
        unsigned* msw = (unsigned*)(means + wv * XS_ * CPB);   // u32 view
        int cur_xi = -1;
        float acc0 = 0.0f, acc1 = 0.0f;
        unsigned cnt = 0u;
        for (unsigned p = p0; p < p1; p += 4) {
            unsigned vv[4]; float2 ff[4];
            #pragma unroll
            for (int j = 0; j < 4; ++j)
                if (p + j < p1) vv[j] = toks[p + j];
            #pragma unroll
            for (int j = 0; j < 4; ++j)
                if (p + j < p1)
                    ff[j] = *(const float2*)&xf[(size_t)(vv[j] & 0xFFFFFu) * C_
                                                + cg * CG_ + 2 * lane];
            #pragma unroll
            for (int j = 0; j < 4; ++j) {
                if (p + j >= p1) break;
                const int xi = (int)(vv[j] >> 20) - xs + 1;   // in [0, 34)
                if (xi != cur_xi) {
                    if (cur_xi >= 0) {
                        const float rcp = 1.0f / ((float)cnt + EPSF);
                        msw[cur_xi * (CPB / 2) + lane] =
                            f2bf(acc0 * rcp) | (f2bf(acc1 * rcp) << 16);
                    }
                    acc0 = acc1 = 0.0f; cnt = 0u; cur_xi = xi;
                }
                acc0 += ff[j].x; acc1 += ff[j].y; ++cnt;
            }
        }
        if (cur_xi >= 0) {
            const float rcp = 1.0f / ((float)cnt + EPSF);
            msw[cur_xi * (CPB / 2) + lane] = f2bf(acc0 * rcp) | (f2bf(acc1 * rcp) << 16);
        }
    }
    __syncthreads();   // B: means + coef ready

    // (4) fill: thread = fixed x (xl) x 16 channels x 2 rows; uniform 9-FMA
    const int xl  = threadIdx.x & 31;
    const int sub = threadIdx.x >> 5;
    const int xi  = xl + 1;
    const int c0  = sub * 16;

    #pragma unroll
    for (int r = 0; r < RY_; ++r) {
        float c9[9];
        #pragma unroll
        for (int j = 0; j < 9; ++j) c9[j] = coef[r][xl][j];
        const unsigned short* M0 = means + (r    ) * XS_ * CPB;
        const unsigned short* M1 = means + (r + 1) * XS_ * CPB;
        const unsigned short* M2 = means + (r + 2) * XS_ * CPB;
        float* op = out + ((size_t)(b * C_ + cg * CG_ + c0)) * HW_
                        + (size_t)(y0 + r) * W_ + xs + xl;

        #pragma unroll
        for (int q = 0; q < 4; ++q) {
            const int cq = c0 + q * 4;
            const int im = (xi - 1) * CPB + cq;
            const int ic = (xi    ) * CPB + cq;
            const int ip = (xi + 1) * CPB + cq;
            float a0[4], a1[4], a2[4], b0[4], b1[4], b2[4], d0[4], d1[4], d2[4];
            bf4_to_f32(&M0[im], a0); bf4_to_f32(&M0[ic], a1); bf4_to_f32(&M0[ip], a2);
            bf4_to_f32(&M1[im], b0); bf4_to_f32(&M1[ic], b1); bf4_to_f32(&M1[ip], b2);
            bf4_to_f32(&M2[im], d0); bf4_to_f32(&M2[ic], d1); bf4_to_f32(&M2[ip], d2);
            #pragma unroll
            for (int k = 0; k < 4; ++k) {
                const float fs = c9[0]*a0[k] + c9[1]*a1[k] + c9[2]*a2[k]
                               + c9[3]*b0[k] + c9[4]*b1[k] + c9[5]*b2[k]
                               + c9[6]*d0[k] + c9[7]*d1[k] + c9[8]*d2[k];
                op[(size_t)(q * 4 + k) * HW_] = fs;
            }
        }
    }
}

extern "C" void kernel_launch(void* const* d_in, const int* in_sizes, int n_in,
                              void* d_out, int out_size, void* d_ws, size_t ws_size,
                              hipStream_t stream) {
    const float* x   = (const float*)d_in[0];   // (B, N, C) f32
    const float* loc = (const float*)d_in[1];   // (B, N, 2) f32
    float* out = (float*)d_out;                 // (B, C, H, W) f32

    unsigned* W32 = (unsigned*)d_ws;
    unsigned* Astart = W32 + OFF_ASTART;
    unsigned* Acur   = W32 + OFF_ACUR;
    unsigned* Bsum   = W32 + OFF_BSUM;
    unsigned* Boff   = W32 + OFF_BOFF;
    unsigned* toks   = W32 + OFF_TOKS;

    hipMemsetAsync(Acur, 0, (size_t)NC_ * sizeof(unsigned), stream);

    count_k  <<<NT_ / 256, 256, 0, stream>>>(loc, Acur);
    scanA    <<<NC_ / 256, 256, 0, stream>>>(Acur, Bsum);
    scanB    <<<1, 512, 0, stream>>>(Bsum, Boff);
    scanC    <<<NC_ / 256, 256, 0, stream>>>(Boff, Astart, Acur);
    fill_bins<<<NT_ / 256, 256, 0, stream>>>(loc, Acur, toks);

    // grid = 8*64*3*2 = 3072 blocks
    fused_k<<<B_ * (H_ / RY_) * 3 * 2, 256, 0, stream>>>(x, Astart, toks, out);
}

// Round 16
// 57.442 us; speedup vs baseline: 1.1730x; 1.0432x over previous
//
#include <hip/hip_runtime.h>

// Problem constants (fixed by setup_inputs in the reference)
#define B_  8
#define N_  3072
#define C_  256
#define H_  128
#define W_  96
#define HW_ (H_ * W_)
#define NC_ (B_ * HW_)          // 98304 cells (~78% EMPTY: 0.25 tokens/cell)
#define NT_ (B_ * N_)           // 24576 tokens
#define EPSF 1e-6f

// Gaussian 3x3, sigma=2 (normalized): center, edge, corner
#define KW0 0.13080118f
#define KW1 0.11543166f
#define KW2 0.10186807f

// fused-kernel tiling: block = (b, 2-row pair, 32-col x-tile, 128-ch group)
#define CG_ 128                 // channels per block (lane covers 2 via float2)
#define XT_ 32                  // x columns written per block
#define XS_ 34                  // staged columns (32 + 2 halo)
#define CPB 132                 // bf16 channel pad (row = 264 B; breaks pow2 banks)
#define RY_ 2                   // output rows per block (4 staged rows, 1 per wave)
#define NWG_ (B_ * (H_ / RY_) * 3 * 2)   // 3072 blocks; 3072 % 8 == 0

// ws layout (u32 units) — round-4-proven layout (ws is actually ~384 MB).
#define OFF_ASTART 0
#define OFF_ACUR   (NC_ + 1)
#define OFF_BSUM   (2 * NC_ + 1)
#define OFF_BOFF   (2 * NC_ + 1 + 384)
#define OFF_TOKS   (2 * NC_ + 1 + 768)

__device__ __forceinline__ unsigned f2bf(float f) {   // RNE f32->bf16 (low 16)
    const unsigned u = __float_as_uint(f);
    return (u + 0x7FFFu + ((u >> 16) & 1u)) >> 16;
}

__device__ __forceinline__ void token_cell(const float* __restrict__ loc, int token,
                                           int& b, int& ix, int& iy) {
    b = token / N_;
    const float lx = fminf(fmaxf(loc[2 * token + 0], -1.0f), 1.0f);
    const float ly = fminf(fmaxf(loc[2 * token + 1], -1.0f), 1.0f);
    const float px = 0.5f * (lx + 1.0f) * (float)W_ - 0.5f;
    const float py = 0.5f * (ly + 1.0f) * (float)H_ - 0.5f;
    ix = (int)rintf(px); ix = min(max(ix, 0), W_ - 1);   // rintf = round-half-even = jnp.round
    iy = (int)rintf(py); iy = min(max(iy, 0), H_ - 1);
}

// Pass 1: histogram tokens into cells
__global__ void count_k(const float* __restrict__ loc, unsigned* __restrict__ cnts) {
    const int token = blockIdx.x * 256 + threadIdx.x;   // NT_ threads
    int b, ix, iy;
    token_cell(loc, token, b, ix, iy);
    atomicAdd(&cnts[b * HW_ + iy * W_ + ix], 1u);
}

// Pass 2a: per-block (256-cell) sums
__global__ void scanA(const unsigned* __restrict__ cnts, unsigned* __restrict__ Bsum) {
    const int i = blockIdx.x * 256 + threadIdx.x;
    int c = (int)cnts[i];
    #pragma unroll
    for (int off = 32; off > 0; off >>= 1) c += __shfl_down(c, off, 64);
    __shared__ int s[4];
    if ((threadIdx.x & 63) == 0) s[threadIdx.x >> 6] = c;
    __syncthreads();
    if (threadIdx.x == 0) Bsum[blockIdx.x] = (unsigned)(s[0] + s[1] + s[2] + s[3]);
}

// Pass 2b: exclusive scan of the 384 block sums (single block)
__global__ void scanB(const unsigned* __restrict__ Bsum, unsigned* __restrict__ Boff) {
    __shared__ unsigned s[512];
    const int t = threadIdx.x;
    const unsigned v = (t < 384) ? Bsum[t] : 0u;
    s[t] = v;
    __syncthreads();
    #pragma unroll
    for (int off = 1; off < 512; off <<= 1) {
        const unsigned a = (t >= off) ? s[t - off] : 0u;
        __syncthreads();
        s[t] += a;
        __syncthreads();
    }
    if (t < 384) Boff[t] = s[t] - v;   // exclusive
}

// Pass 2c: per-block exclusive scan + block offset -> Astart (and cursor copy)
__global__ void scanC(const unsigned* __restrict__ Boff,
                      unsigned* __restrict__ Astart, unsigned* __restrict__ Acur) {
    __shared__ unsigned s[256];
    const int t = threadIdx.x;
    const int i = blockIdx.x * 256 + t;
    const unsigned v = Acur[i];        // counts currently live in Acur
    s[t] = v;
    __syncthreads();
    #pragma unroll
    for (int off = 1; off < 256; off <<= 1) {
        const unsigned a = (t >= off) ? s[t - off] : 0u;
        __syncthreads();
        s[t] += a;
        __syncthreads();
    }
    const unsigned excl = s[t] - v + Boff[blockIdx.x];
    Astart[i] = excl;
    Acur[i]   = excl;                  // cursor starts at bin start
    if (i == 0) Astart[NC_] = NT_;     // total
}

// Pass 3: scatter token ids (packed with x) into bins
__global__ void fill_bins(const float* __restrict__ loc,
                          unsigned* __restrict__ Acur, unsigned* __restrict__ toks) {
    const int token = blockIdx.x * 256 + threadIdx.x;
    int b, ix, iy;
    token_cell(loc, token, b, ix, iy);
    const unsigned pos = atomicAdd(&Acur[b * HW_ + iy * W_ + ix], 1u);
    toks[pos] = ((unsigned)ix << 20) | (unsigned)token;
}

// unpack 4 bf16 (8B, aligned) -> 4 f32
__device__ __forceinline__ void bf4_to_f32(const unsigned short* p, float* f) {
    const uint2 v = *(const uint2*)p;
    f[0] = __uint_as_float(v.x << 16);
    f[1] = __uint_as_float(v.x & 0xFFFF0000u);
    f[2] = __uint_as_float(v.y << 16);
    f[3] = __uint_as_float(v.y & 0xFFFF0000u);
}

// Pass 4 (FUSED, 2 rows/block, branchless fill, XCD-swizzled):
//   blockIdx is remapped so each XCD's contiguous chunk of 384 blocks covers
//   EXACTLY ONE batch image b -> that batch's xf rows (~3 MB) + toks + Astart
//   fit the XCD's private 4 MB L2, turning the gather's dependent loads into
//   L2 hits. (3072 % 8 == 0 -> bijective chunked swizzle.)
__global__ __launch_bounds__(256) void fused_k(const float* __restrict__ xf,
        const unsigned* __restrict__ Astart, const unsigned* __restrict__ toks,
        float* __restrict__ out) {
    // XCD-aware swizzle: HW round-robins consecutive blockIdx across 8 XCDs.
    const int blk = (blockIdx.x & 7) * (NWG_ / 8) + (blockIdx.x >> 3);
    const int cg = blk & 1;              // ((b*64 + yp)*3 + xt)*2 + cg
    const int t2 = blk >> 1;
    const int xt = t2 % 3;
    const int t3 = t2 / 3;
    const int yp = t3 & 63;
    const int b  = t3 >> 6;
    const int y0 = yp * RY_;
    const int xs = xt * XT_;
    const int lane = threadIdx.x & 63;
    const int wv = threadIdx.x >> 6;

    __shared__ __align__(16) unsigned short means[4 * XS_ * CPB];   // 35904 B
    __shared__ unsigned long long cmask[4];
    __shared__ float coef[RY_][XT_][10];                            // 2560 B

    // (1) per-wave Astart stage for row y0-1+wv (issues early; latency
    //     overlaps the zero-init below). OOB rows -> cmask 0, empty range.
    const int yg = y0 - 1 + wv;
    const bool inrow = ((unsigned)yg < (unsigned)H_);
    unsigned p0, p1;
    {
        unsigned a = 0u;
        if (inrow && lane < XS_ + 1) {
            int g = xs - 1 + lane;                 // [xs-1, xs+33]
            g = min(max(g, 0), W_);                // Astart[..+W_] = row end
            a = Astart[b * HW_ + yg * W_ + g];
        }
        const unsigned an = __shfl_down(a, 1, 64);
        const unsigned long long mask = __ballot(lane < XS_ && an > a);
        if (lane == 0) cmask[wv] = mask;
        p0 = __shfl(a, 0, 64);
        p1 = __shfl(a, XS_, 64);
    }

    // (2) zero-init means (bf16 +0.0 = 0x0000); empty cells stay exactly 0
    {
        uint4* p4 = (uint4*)means;
        for (int i = threadIdx.x; i < 4 * XS_ * CPB / 8; i += 256)
            p4[i] = make_uint4(0u, 0u, 0u, 0u);
    }
    __syncthreads();   // A: init + cmask ready

    // (3a) wave 0: per-cell coefficient table (64 cells = 2 rows x 32 x)
    if (wv == 0) {
        const int r  = lane >> 5;
        const int xl = lane & 31;
        const int xi = xl + 1;
        const unsigned long long cm0 = cmask[r], cm1 = cmask[r + 1],
                                 cm2 = cmask[r + 2];
        const float w0 = ((cm0 >> (xi - 1)) & 1ULL) ? KW2 : 0.0f;
        const float w1 = ((cm0 >> xi)       & 1ULL) ? KW1 : 0.0f;
        const float w2 = ((cm0 >> (xi + 1)) & 1ULL) ? KW2 : 0.0f;
        const float w3 = ((cm1 >> (xi - 1)) & 1ULL) ? KW1 : 0.0f;
        const float w5 = ((cm1 >> (xi + 1)) & 1ULL) ? KW1 : 0.0f;
        const float w6 = ((cm2 >> (xi - 1)) & 1ULL) ? KW2 : 0.0f;
        const float w7 = ((cm2 >> xi)       & 1ULL) ? KW1 : 0.0f;
        const float w8 = ((cm2 >> (xi + 1)) & 1ULL) ? KW2 : 0.0f;
        const bool ne  = (cm1 >> xi) & 1ULL;
        const float ms = ((w0 + w2) + (w6 + w8)) + ((w1 + w7) + (w3 + w5));
        const float inv = ne ? 0.0f : 1.0f / (ms + EPSF);   // ms==0 -> all 0
        coef[r][xl][0] = w0 * inv;
        coef[r][xl][1] = w1 * inv;
        coef[r][xl][2] = w2 * inv;
        coef[r][xl][3] = w3 * inv;
        coef[r][xl][4] = ne ? 1.0f : 0.0f;   // self (nonempty copy)
        coef[r][xl][5] = w5 * inv;
        coef[r][xl][6] = w6 * inv;
        coef[r][xl][7] = w7 * inv;
        coef[r][xl][8] = w8 * inv;
    }

    // (3b) all waves: batch-4 contiguous CSR walk of [p0,p1) into slot wv
    if (inrow) {
        unsigned* msw = (unsigned*)(means + wv * XS_ * CPB);   // u32 view
        int cur_xi = -1;
        float acc0 = 0.0f, acc1 = 0.0f;
        unsigned cnt = 0u;
        for (unsigned p = p0; p < p1; p += 4) {
            unsigned vv[4]; float2 ff[4];
            #pragma unroll
            for (int j = 0; j < 4; ++j)
                if (p + j < p1) vv[j] = toks[p + j];
            #pragma unroll
            for (int j = 0; j < 4; ++j)
                if (p + j < p1)
                    ff[j] = *(const float2*)&xf[(size_t)(vv[j] & 0xFFFFFu) * C_
                                                + cg * CG_ + 2 * lane];
            #pragma unroll
            for (int j = 0; j < 4; ++j) {
                if (p + j >= p1) break;
                const int xi = (int)(vv[j] >> 20) - xs + 1;   // in [0, 34)
                if (xi != cur_xi) {
                    if (cur_xi >= 0) {
                        const float rcp = 1.0f / ((float)cnt + EPSF);
                        msw[cur_xi * (CPB / 2) + lane] =
                            f2bf(acc0 * rcp) | (f2bf(acc1 * rcp) << 16);
                    }
                    acc0 = acc1 = 0.0f; cnt = 0u; cur_xi = xi;
                }
                acc0 += ff[j].x; acc1 += ff[j].y; ++cnt;
            }
        }
        if (cur_xi >= 0) {
            const float rcp = 1.0f / ((float)cnt + EPSF);
            msw[cur_xi * (CPB / 2) + lane] = f2bf(acc0 * rcp) | (f2bf(acc1 * rcp) << 16);
        }
    }
    __syncthreads();   // B: means + coef ready

    // (4) fill: thread = fixed x (xl) x 16 channels x 2 rows; uniform 9-FMA
    const int xl  = threadIdx.x & 31;
    const int sub = threadIdx.x >> 5;
    const int xi  = xl + 1;
    const int c0  = sub * 16;

    #pragma unroll
    for (int r = 0; r < RY_; ++r) {
        float c9[9];
        #pragma unroll
        for (int j = 0; j < 9; ++j) c9[j] = coef[r][xl][j];
        const unsigned short* M0 = means + (r    ) * XS_ * CPB;
        const unsigned short* M1 = means + (r + 1) * XS_ * CPB;
        const unsigned short* M2 = means + (r + 2) * XS_ * CPB;
        float* op = out + ((size_t)(b * C_ + cg * CG_ + c0)) * HW_
                        + (size_t)(y0 + r) * W_ + xs + xl;

        #pragma unroll
        for (int q = 0; q < 4; ++q) {
            const int cq = c0 + q * 4;
            const int im = (xi - 1) * CPB + cq;
            const int ic = (xi    ) * CPB + cq;
            const int ip = (xi + 1) * CPB + cq;
            float a0[4], a1[4], a2[4], b0[4], b1[4], b2[4], d0[4], d1[4], d2[4];
            bf4_to_f32(&M0[im], a0); bf4_to_f32(&M0[ic], a1); bf4_to_f32(&M0[ip], a2);
            bf4_to_f32(&M1[im], b0); bf4_to_f32(&M1[ic], b1); bf4_to_f32(&M1[ip], b2);
            bf4_to_f32(&M2[im], d0); bf4_to_f32(&M2[ic], d1); bf4_to_f32(&M2[ip], d2);
            #pragma unroll
            for (int k = 0; k < 4; ++k) {
                const float fs = c9[0]*a0[k] + c9[1]*a1[k] + c9[2]*a2[k]
                               + c9[3]*b0[k] + c9[4]*b1[k] + c9[5]*b2[k]
                               + c9[6]*d0[k] + c9[7]*d1[k] + c9[8]*d2[k];
                op[(size_t)(q * 4 + k) * HW_] = fs;
            }
        }
    }
}

extern "C" void kernel_launch(void* const* d_in, const int* in_sizes, int n_in,
                              void* d_out, int out_size, void* d_ws, size_t ws_size,
                              hipStream_t stream) {
    const float* x   = (const float*)d_in[0];   // (B, N, C) f32
    const float* loc = (const float*)d_in[1];   // (B, N, 2) f32
    float* out = (float*)d_out;                 // (B, C, H, W) f32

    unsigned* W32 = (unsigned*)d_ws;
    unsigned* Astart = W32 + OFF_ASTART;
    unsigned* Acur   = W32 + OFF_ACUR;
    unsigned* Bsum   = W32 + OFF_BSUM;
    unsigned* Boff   = W32 + OFF_BOFF;
    unsigned* toks   = W32 + OFF_TOKS;

    hipMemsetAsync(Acur, 0, (size_t)NC_ * sizeof(unsigned), stream);

    count_k  <<<NT_ / 256, 256, 0, stream>>>(loc, Acur);
    scanA    <<<NC_ / 256, 256, 0, stream>>>(Acur, Bsum);
    scanB    <<<1, 512, 0, stream>>>(Bsum, Boff);
    scanC    <<<NC_ / 256, 256, 0, stream>>>(Boff, Astart, Acur);
    fill_bins<<<NT_ / 256, 256, 0, stream>>>(loc, Acur, toks);

    // grid = 3072 blocks (XCD-swizzled inside the kernel)
    fused_k<<<NWG_, 256, 0, stream>>>(x, Astart, toks, out);
}